// Round 11
// baseline (128.841 us; speedup 1.0000x reference)
//
#include <hip/hip_runtime.h>
#include <math.h>

#define NN 768
#define CC 256
#define TI 3     // rows per k_prep block (row-triple)
#define RT 12    // rows per k_attn block (4 triples)
#define JCC 256  // j columns per k_attn block
#define NJC 3    // j chunks: 3 * 256 = 768
#define PSTR 20  // pe row stride in floats: 16B-aligned, breaks worst conflicts

__device__ __forceinline__ float leaky(float x) { return x >= 0.0f ? x : 0.2f * x; }

__device__ __forceinline__ float waveMax(float v) {
    #pragma unroll
    for (int o = 32; o > 0; o >>= 1) v = fmaxf(v, __shfl_xor(v, o, 64));
    return v;
}
__device__ __forceinline__ float waveSum(float v) {
    #pragma unroll
    for (int o = 32; o > 0; o >>= 1) v += __shfl_xor(v, o, 64);
    return v;
}

__device__ __forceinline__ void acc_row(float4& a, float ur, float w4, const float4& gv) {
    a.x = fmaf(w4, fabsf(ur + gv.x), a.x);
    a.y = fmaf(w4, fabsf(ur + gv.y), a.y);
    a.z = fmaf(w4, fabsf(ur + gv.z), a.z);
    a.w = fmaf(w4, fabsf(ur + gv.w), a.w);
}
__device__ __forceinline__ void fma4(float4& h, float e, const float4& fv) {
    h.x = fmaf(e, fv.x, h.x);
    h.y = fmaf(e, fv.y, h.y);
    h.z = fmaf(e, fv.z, h.z);
    h.w = fmaf(e, fv.w, h.w);
}

// Kernel 1 (unchanged): f = features @ FC; g[c][j] = w1*f[j][c]+b;
// D0/D1 = per-row linear-term dots; ut4[triple][c] = {w0*f_r0[c], w0*f_r1[c],
// w0*f_r2[c], 0.4*lin_w[c]}.
__global__ __launch_bounds__(768) void k_prep(
    const float* __restrict__ features,
    const float* __restrict__ FC,
    const float* __restrict__ fc_w,
    const float* __restrict__ fc_b,
    const float* __restrict__ lin_w,
    float* __restrict__ f,
    float* __restrict__ g,
    float* __restrict__ D0,
    float* __restrict__ D1,
    float4* __restrict__ ut4)
{
    __shared__ float sA[TI * CC];
    __shared__ float sF[TI * CC];
    __shared__ float sredD[12], sredW[12];

    const int t  = threadIdx.x;
    const int r  = t >> 8;
    const int c  = t & 255;
    const int i0 = blockIdx.x * TI;

    sA[r * CC + c] = features[(i0 + r) * CC + c];
    __syncthreads();

    float a = 0.f;
    const float* fcp = FC + c;
    const float* ap  = sA + r * CC;
    #pragma unroll 8
    for (int k = 0; k < CC; ++k)
        a = fmaf(ap[k], fcp[k * CC], a);

    const float w1 = fc_w[1], b = fc_b[0];
    f[(i0 + r) * CC + c] = a;
    g[c * NN + i0 + r]   = fmaf(w1, a, b);
    sF[r * CC + c] = a;

    const float lw = lin_w[c];
    float dv = waveSum(lw * a);
    float wv = waveSum(lw);
    const int wid = t >> 6;
    if ((t & 63) == 0) { sredD[wid] = dv; sredW[wid] = wv; }
    __syncthreads();
    if (t < TI) {
        float D = sredD[t*4] + sredD[t*4+1] + sredD[t*4+2] + sredD[t*4+3];
        float W = sredW[t*4] + sredW[t*4+1] + sredW[t*4+2] + sredW[t*4+3];
        D0[i0 + t] = fc_w[0] * D;
        D1[i0 + t] = fmaf(w1, D, b * W);
    }
    if (t < CC) {
        const float w0 = fc_w[0];
        ut4[blockIdx.x * CC + t] = make_float4(w0 * sF[t],
                                               w0 * sF[CC + t],
                                               w0 * sF[2*CC + t],
                                               0.4f * lin_w[t]);
    }
}

// Kernel 2: 192 blocks (64 row-tiles of 12 x 3 j-chunks of 256) x 256 threads.
// RT=12 cuts the g/f re-read traffic to 96 MB (the RT=3 variants' 384 MB at
// ~15 TB/s WAS the invariant ~26 us). Mechanics from round 10: float4 g loads
// (latency-proof), u via LDS b128 broadcasts, pe LDS round-trip for phase 3.
__global__ __launch_bounds__(256) void k_attn(
    const float* __restrict__ f,      // [N][C]
    const float* __restrict__ g,      // [C][N]
    const float4* __restrict__ ut4,   // [N/3][C]
    const float* __restrict__ D0,     // [N]
    const float* __restrict__ D1,     // [N]
    const float* __restrict__ coords, // [N][3]
    const float* __restrict__ sc_w,
    const float* __restrict__ sc_b,
    const float* __restrict__ lin_w,  // [C+3]
    const float* __restrict__ lin_b,
    float* __restrict__ hp,           // [NJC][N][C] partial sums
    float* __restrict__ Mp,           // [N][NJC] partial max
    float* __restrict__ Lp)           // [N][NJC] partial expsum
{
    __shared__ float4 su4[4][CC];       // 16 KB: staged u, 4 row-triples
    __shared__ float  sred[4][RT][CC];  // 48 KB: phase-1 spart, reused as phase-3 hpart
    __shared__ float  pe[JCC][PSTR];    // 20 KB: exp values, padded rows
    __shared__ float  sredm[4][RT];
    __shared__ float  sreds[4][RT];

    const int t    = threadIdx.x;
    const int it   = blockIdx.x & 63;   // row-tile (12 rows)
    const int jc   = blockIdx.x >> 6;   // j-chunk 0..2
    const int i0   = it * RT;
    const int jb   = jc * JCC;
    const int w    = t >> 6;
    const int lane = t & 63;

    // stage u for the 4 row-triples of this tile (4 coalesced 4 KB reads)
    #pragma unroll
    for (int q = 0; q < 4; ++q)
        su4[q][t] = ut4[(size_t)(it * 4 + q) * CC + t];
    __syncthreads();

    // ---- Phase 1: wave owns c-slice [64w,64w+64); lane owns j-quad jb+4*lane.
    float4 acc[RT];
    #pragma unroll
    for (int r = 0; r < RT; ++r) acc[r] = make_float4(0.f, 0.f, 0.f, 0.f);
    const float4* gq = (const float4*)g + (size_t)(w << 6) * (NN/4) + (jb >> 2) + lane;
    #pragma unroll 4
    for (int cc = 0; cc < 64; ++cc) {
        float4 gv = gq[(size_t)cc * (NN/4)];   // coalesced 1KB/wave, L2-resident
        const int c = (w << 6) + cc;
        #pragma unroll
        for (int q = 0; q < 4; ++q) {
            float4 u = su4[q][c];              // ds_read_b128 broadcast
            acc_row(acc[3*q+0], u.x, u.w, gv);
            acc_row(acc[3*q+1], u.y, u.w, gv);
            acc_row(acc[3*q+2], u.z, u.w, gv);
        }
    }
    #pragma unroll
    for (int r = 0; r < RT; ++r)
        *(float4*)&sred[w][r][4*lane] = acc[r];
    __syncthreads();

    // ---- Tail: thread t owns j = jb + t; full scores for 12 rows ----
    const int j = jb + t;
    const float sw0 = sc_w[0], sw1 = sc_w[1], sb = sc_b[0], lb = lin_b[0];
    const float lw30 = lin_w[CC], lw31 = lin_w[CC+1], lw32 = lin_w[CC+2];
    const float cj0 = fmaf(sw1, coords[j*3+0], sb);
    const float cj1 = fmaf(sw1, coords[j*3+1], sb);
    const float cj2 = fmaf(sw1, coords[j*3+2], sb);
    const float d1  = D1[j];
    float scv[RT];
    #pragma unroll
    for (int r = 0; r < RT; ++r) {
        const int i = i0 + r;
        float a = sred[0][r][t] + sred[1][r][t] + sred[2][r][t] + sred[3][r][t];
        float sd = lw30 * leaky(fmaf(sw0, coords[i*3+0], cj0))
                 + lw31 * leaky(fmaf(sw0, coords[i*3+1], cj1))
                 + lw32 * leaky(fmaf(sw0, coords[i*3+2], cj2));
        scv[r] = leaky(a + sd + 0.6f * (D0[i] + d1) + lb);
    }

    // ---- Phase 2: partial softmax (12 rows x this block's 256 j) ----
    #pragma unroll
    for (int r = 0; r < RT; ++r) {
        float v = waveMax(scv[r]);
        if (lane == 0) sredm[w][r] = v;
    }
    __syncthreads();
    float m[RT];
    #pragma unroll
    for (int r = 0; r < RT; ++r)
        m[r] = fmaxf(fmaxf(sredm[0][r], sredm[1][r]),
                     fmaxf(sredm[2][r], sredm[3][r]));
    float e[RT];
    #pragma unroll
    for (int r = 0; r < RT; ++r) {
        e[r] = __expf(scv[r] - m[r]);
        pe[t][r] = e[r];
    }
    #pragma unroll
    for (int r = 0; r < RT; ++r) {
        float v = waveSum(e[r]);
        if (lane == 0) sreds[w][r] = v;
    }
    __syncthreads();   // publishes pe + sreds
    if (t < RT) {
        float l  = sreds[0][t] + sreds[1][t] + sreds[2][t] + sreds[3][t];
        float mm = fmaxf(fmaxf(sredm[0][t], sredm[1][t]),
                         fmaxf(sredm[2][t], sredm[3][t]));
        Mp[(i0 + t) * NJC + jc] = mm;
        Lp[(i0 + t) * NJC + jc] = l;
    }

    // ---- Phase 3: wave owns j-slice [64w,64w+64); lane owns c-quad 4*lane ----
    float4 h[RT];
    #pragma unroll
    for (int r = 0; r < RT; ++r) h[r] = make_float4(0.f, 0.f, 0.f, 0.f);
    const float4* f4 = (const float4*)f;   // [N][64] float4
    const int jsl = w * 64;
    #pragma unroll 2
    for (int jx = 0; jx < 64; ++jx) {
        const int jl = jsl + jx;
        float4 fv = f4[(size_t)(jb + jl) * 64 + lane];      // coalesced 1KB/wave
        const float4* pe4 = (const float4*)&pe[jl][0];      // aligned b128 broadcasts
        float4 e0 = pe4[0], e1 = pe4[1], e2 = pe4[2];
        fma4(h[0],  e0.x, fv); fma4(h[1],  e0.y, fv);
        fma4(h[2],  e0.z, fv); fma4(h[3],  e0.w, fv);
        fma4(h[4],  e1.x, fv); fma4(h[5],  e1.y, fv);
        fma4(h[6],  e1.z, fv); fma4(h[7],  e1.w, fv);
        fma4(h[8],  e2.x, fv); fma4(h[9],  e2.y, fv);
        fma4(h[10], e2.z, fv); fma4(h[11], e2.w, fv);
    }
    #pragma unroll
    for (int r = 0; r < RT; ++r)
        *(float4*)&sred[w][r][4*lane] = h[r];   // safe: last sred read was pre-barrier
    __syncthreads();

    // ---- Reduce the 4 wave-partials per row; store hp ----
    #pragma unroll
    for (int r = 0; r < RT; ++r) {
        float hh = sred[0][r][t] + sred[1][r][t] + sred[2][r][t] + sred[3][r][t];
        hp[((size_t)jc * NN + i0 + r) * CC + t] = hh;
    }
}

// Kernel 3: combine the 3 j-chunk partials per row, normalize, elu.
__global__ __launch_bounds__(256) void k_comb(
    const float* __restrict__ hp,
    const float* __restrict__ Mp,
    const float* __restrict__ Lp,
    float* __restrict__ out)
{
    const int t = threadIdx.x;
    const int i = blockIdx.x;

    float m0 = Mp[i*NJC+0], m1 = Mp[i*NJC+1], m2 = Mp[i*NJC+2];
    float M  = fmaxf(fmaxf(m0, m1), m2);
    float w0 = __expf(m0 - M), w1 = __expf(m1 - M), w2 = __expf(m2 - M);
    float den = w0*Lp[i*NJC+0] + w1*Lp[i*NJC+1] + w2*Lp[i*NJC+2];
    float inv = 1.0f / den;

    float num = w0 * hp[((size_t)0*NN + i)*CC + t]
              + w1 * hp[((size_t)1*NN + i)*CC + t]
              + w2 * hp[((size_t)2*NN + i)*CC + t];
    float v = num * inv;
    out[i*CC + t] = (v > 0.f) ? v : (__expf(v) - 1.0f);
}

extern "C" void kernel_launch(void* const* d_in, const int* in_sizes, int n_in,
                              void* d_out, int out_size, void* d_ws, size_t ws_size,
                              hipStream_t stream) {
    const float* features = (const float*)d_in[0];
    const float* coords   = (const float*)d_in[1];
    // d_in[2] = adj, unused by forward
    const float* FC       = (const float*)d_in[3];
    const float* fc_w     = (const float*)d_in[4];
    const float* fc_b     = (const float*)d_in[5];
    const float* sc_w     = (const float*)d_in[6];
    const float* sc_b     = (const float*)d_in[7];
    const float* lin_w    = (const float*)d_in[8];
    const float* lin_b    = (const float*)d_in[9];
    float* out = (float*)d_out;

    float* f  = (float*)d_ws;              // N*C
    float* g  = f  + NN*CC;                // C*N
    float* D0 = g  + CC*NN;                // N
    float* D1 = D0 + NN;                   // N
    float* Mp = D1 + NN;                   // N*NJC
    float* Lp = Mp + NN*NJC;               // N*NJC
    float* hp = Lp + NN*NJC;               // NJC*N*C
    float4* ut4;
    {
        size_t off = (size_t)((char*)(hp + (size_t)NJC*NN*CC) - (char*)d_ws);
        off = (off + 15) & ~(size_t)15;
        ut4 = (float4*)((char*)d_ws + off); // (N/3)*C float4, 16B-aligned
    }

    k_prep<<<NN/TI, 768, 0, stream>>>(features, FC, fc_w, fc_b, lin_w, f, g, D0, D1, ut4);
    k_attn<<<(NN/RT)*NJC, 256, 0, stream>>>(f, g, ut4, D0, D1, coords, sc_w, sc_b,
                                            lin_w, lin_b, hp, Mp, Lp);
    k_comb<<<NN, 256, 0, stream>>>(hp, Mp, Lp, out);
}

// Round 12
// 113.792 us; speedup vs baseline: 1.1322x; 1.1322x over previous
//
#include <hip/hip_runtime.h>
#include <math.h>

#define NN 768
#define CC 256
#define TI 3     // rows per block (both kernels)
#define JC 256   // j columns per k_attn block
#define NJC 3    // j chunks: 3 * 256 = 768

__device__ __forceinline__ float leaky(float x) { return x >= 0.0f ? x : 0.2f * x; }

__device__ __forceinline__ float rl(float v, int l) {   // wave broadcast, VALU pipe
    return __uint_as_float(__builtin_amdgcn_readlane(__float_as_uint(v), l));
}

__device__ __forceinline__ float waveMax(float v) {
    #pragma unroll
    for (int o = 32; o > 0; o >>= 1) v = fmaxf(v, __shfl_xor(v, o, 64));
    return v;
}
__device__ __forceinline__ float waveSum(float v) {
    #pragma unroll
    for (int o = 32; o > 0; o >>= 1) v += __shfl_xor(v, o, 64);
    return v;
}

__device__ __forceinline__ void acc_row(float4& a, float ur, float w4, const float4& gv) {
    a.x = fmaf(w4, fabsf(ur + gv.x), a.x);
    a.y = fmaf(w4, fabsf(ur + gv.y), a.y);
    a.z = fmaf(w4, fabsf(ur + gv.z), a.z);
    a.w = fmaf(w4, fabsf(ur + gv.w), a.w);
}
__device__ __forceinline__ void fma4(float4& h, float e, const float4& fv) {
    h.x = fmaf(e, fv.x, h.x);
    h.y = fmaf(e, fv.y, h.y);
    h.z = fmaf(e, fv.z, h.z);
    h.w = fmaf(e, fv.w, h.w);
}

// Kernel 1 (unchanged): f = features @ FC; g[c][j] = w1*f[j][c]+b;
// D0/D1 = per-row linear-term dots; ut4[triple][c] = {w0*f_r0[c], w0*f_r1[c],
// w0*f_r2[c], 0.4*lin_w[c]}.
__global__ __launch_bounds__(768) void k_prep(
    const float* __restrict__ features,
    const float* __restrict__ FC,
    const float* __restrict__ fc_w,
    const float* __restrict__ fc_b,
    const float* __restrict__ lin_w,
    float* __restrict__ f,
    float* __restrict__ g,
    float* __restrict__ D0,
    float* __restrict__ D1,
    float4* __restrict__ ut4)
{
    __shared__ float sA[TI * CC];
    __shared__ float sF[TI * CC];
    __shared__ float sredD[12], sredW[12];

    const int t  = threadIdx.x;
    const int r  = t >> 8;
    const int c  = t & 255;
    const int i0 = blockIdx.x * TI;

    sA[r * CC + c] = features[(i0 + r) * CC + c];
    __syncthreads();

    float a = 0.f;
    const float* fcp = FC + c;
    const float* ap  = sA + r * CC;
    #pragma unroll 8
    for (int k = 0; k < CC; ++k)
        a = fmaf(ap[k], fcp[k * CC], a);

    const float w1 = fc_w[1], b = fc_b[0];
    f[(i0 + r) * CC + c] = a;
    g[c * NN + i0 + r]   = fmaf(w1, a, b);
    sF[r * CC + c] = a;

    const float lw = lin_w[c];
    float dv = waveSum(lw * a);
    float wv = waveSum(lw);
    const int wid = t >> 6;
    if ((t & 63) == 0) { sredD[wid] = dv; sredW[wid] = wv; }
    __syncthreads();
    if (t < TI) {
        float D = sredD[t*4] + sredD[t*4+1] + sredD[t*4+2] + sredD[t*4+3];
        float W = sredW[t*4] + sredW[t*4+1] + sredW[t*4+2] + sredW[t*4+3];
        D0[i0 + t] = fc_w[0] * D;
        D1[i0 + t] = fmaf(w1, D, b * W);
    }
    if (t < CC) {
        const float w0 = fc_w[0];
        ut4[blockIdx.x * CC + t] = make_float4(w0 * sF[t],
                                               w0 * sF[CC + t],
                                               w0 * sF[2*CC + t],
                                               0.4f * lin_w[t]);
    }
}

// Kernel 2: round-10 structure (768 blocks x 256 thr, 3 blocks/CU) with the
// two hot LDS broadcasts replaced by v_readlane wave-broadcasts:
//  - phase 1: wave preloads its 64-c u-slice into ONE float4/lane; 4 readlanes
//    per c replace the ds_read_b128 (DS ~18k -> ~3k cyc/CU).
//  - phase 3: e already lives in the owning lanes (thread t owns j=jb+t);
//    3 readlanes per jx replace the pe LDS round-trip entirely.
__global__ __launch_bounds__(256) void k_attn(
    const float* __restrict__ f,      // [N][C]
    const float* __restrict__ g,      // [C][N]
    const float4* __restrict__ ut4,   // [N/3][C]
    const float* __restrict__ D0,     // [N]
    const float* __restrict__ D1,     // [N]
    const float* __restrict__ coords, // [N][3]
    const float* __restrict__ sc_w,
    const float* __restrict__ sc_b,
    const float* __restrict__ lin_w,  // [C+3]
    const float* __restrict__ lin_b,
    float* __restrict__ hp,           // [NJC][N][C] partial sums
    float* __restrict__ Mp,           // [N][NJC] partial max
    float* __restrict__ Lp)           // [N][NJC] partial expsum
{
    __shared__ float  spart[4][TI][JC]; // 12 KB: per-c-slice score partials
    __shared__ float  hpart[4][TI][CC]; // 12 KB: per-wave h partials
    __shared__ float4 sredm4[4];
    __shared__ float4 sreds4[4];

    const int t    = threadIdx.x;
    const int it   = blockIdx.x & 255;  // row-triple
    const int jc   = blockIdx.x >> 8;   // j-chunk 0..2
    const int i0   = it * TI;
    const int jb   = jc * JC;
    const int j    = jb + t;
    const int w    = t >> 6;
    const int lane = t & 63;

    // wave w's 64-c u-slice: lane holds the quad for c = 64w + lane
    float4 ureg = ut4[(size_t)it * CC + (w << 6) + lane];   // coalesced b128

    // ---- Phase 1: wave owns c-slice [64w,64w+64); lane owns j-quad jb+4*lane ----
    float4 a0 = make_float4(0.f,0.f,0.f,0.f);
    float4 a1 = a0, a2 = a0;
    const float4* gq = (const float4*)g + (size_t)(w << 6) * (NN/4) + (jb >> 2) + lane;
    #pragma unroll 8
    for (int cc = 0; cc < 64; ++cc) {
        float4 gv = gq[cc * (NN/4)];   // coalesced 1KB/wave
        float u0 = rl(ureg.x, cc);     // VALU-pipe broadcast, no DS
        float u1 = rl(ureg.y, cc);
        float u2 = rl(ureg.z, cc);
        float w4 = rl(ureg.w, cc);
        acc_row(a0, u0, w4, gv);
        acc_row(a1, u1, w4, gv);
        acc_row(a2, u2, w4, gv);
    }
    *(float4*)&spart[w][0][4*lane] = a0;
    *(float4*)&spart[w][1][4*lane] = a1;
    *(float4*)&spart[w][2][4*lane] = a2;
    __syncthreads();

    // ---- Tail: thread t owns j = jb + t ----
    float accs[3];
    #pragma unroll
    for (int rr = 0; rr < TI; ++rr)
        accs[rr] = spart[0][rr][t] + spart[1][rr][t]
                 + spart[2][rr][t] + spart[3][rr][t];

    const float sw0 = sc_w[0], sw1 = sc_w[1], sb = sc_b[0], lb = lin_b[0];
    const float lw30 = lin_w[CC], lw31 = lin_w[CC+1], lw32 = lin_w[CC+2];
    const float cj0 = fmaf(sw1, coords[j*3+0], sb);
    const float cj1 = fmaf(sw1, coords[j*3+1], sb);
    const float cj2 = fmaf(sw1, coords[j*3+2], sb);
    const float d1  = D1[j];
    float scv[3];
    #pragma unroll
    for (int rr = 0; rr < TI; ++rr) {
        const int i = i0 + rr;
        float sd = lw30 * leaky(fmaf(sw0, coords[i*3+0], cj0))
                 + lw31 * leaky(fmaf(sw0, coords[i*3+1], cj1))
                 + lw32 * leaky(fmaf(sw0, coords[i*3+2], cj2));
        scv[rr] = leaky(accs[rr] + sd + 0.6f * (D0[i] + d1) + lb);
    }

    // ---- Phase 2: partial softmax over this block's 256 j ----
    {
        float v0 = waveMax(scv[0]);
        float v1 = waveMax(scv[1]);
        float v2 = waveMax(scv[2]);
        if (lane == 0) sredm4[w] = make_float4(v0, v1, v2, 0.f);
    }
    __syncthreads();
    float m[TI];
    {
        float4 x0 = sredm4[0], x1 = sredm4[1], x2 = sredm4[2], x3 = sredm4[3];
        m[0] = fmaxf(fmaxf(x0.x, x1.x), fmaxf(x2.x, x3.x));
        m[1] = fmaxf(fmaxf(x0.y, x1.y), fmaxf(x2.y, x3.y));
        m[2] = fmaxf(fmaxf(x0.z, x1.z), fmaxf(x2.z, x3.z));
    }
    float e0 = __expf(scv[0] - m[0]);
    float e1 = __expf(scv[1] - m[1]);
    float e2 = __expf(scv[2] - m[2]);
    {
        float v0 = waveSum(e0);
        float v1 = waveSum(e1);
        float v2 = waveSum(e2);
        if (lane == 0) sreds4[w] = make_float4(v0, v1, v2, 0.f);
    }
    __syncthreads();   // publishes sreds4
    if (t < TI) {
        float4 s0 = sreds4[0], s1 = sreds4[1], s2 = sreds4[2], s3 = sreds4[3];
        float l = (t == 0) ? (s0.x + s1.x + s2.x + s3.x)
                : (t == 1) ? (s0.y + s1.y + s2.y + s3.y)
                           : (s0.z + s1.z + s2.z + s3.z);
        float mm = (t == 0) ? m[0] : (t == 1) ? m[1] : m[2];
        Mp[(i0 + t) * NJC + jc] = mm;
        Lp[(i0 + t) * NJC + jc] = l;
    }

    // ---- Phase 3: wave w owns j-slice [64w,64w+64) — exactly the j's its own
    // lanes hold e for; broadcast via readlane, lane owns c-quad 4*lane ----
    float4 h0 = make_float4(0.f,0.f,0.f,0.f);
    float4 h1 = h0, h2 = h0;
    const float4* f4 = (const float4*)f;   // [N][64] float4
    const int jsl = w * 64;
    #pragma unroll 8
    for (int jx = 0; jx < 64; ++jx) {
        float4 fv = f4[(size_t)(jb + jsl + jx) * 64 + lane];  // coalesced 1KB/wave
        float se0 = rl(e0, jx);
        float se1 = rl(e1, jx);
        float se2 = rl(e2, jx);
        fma4(h0, se0, fv);
        fma4(h1, se1, fv);
        fma4(h2, se2, fv);
    }
    *(float4*)&hpart[w][0][4*lane] = h0;
    *(float4*)&hpart[w][1][4*lane] = h1;
    *(float4*)&hpart[w][2][4*lane] = h2;
    __syncthreads();

    // ---- Reduce the 4 wave-partials per row; store hp ----
    #pragma unroll
    for (int r = 0; r < TI; ++r) {
        float h = hpart[0][r][t] + hpart[1][r][t] + hpart[2][r][t] + hpart[3][r][t];
        hp[((size_t)jc * NN + i0 + r) * CC + t] = h;
    }
}

// Kernel 3: combine the 3 j-chunk partials per row, normalize, elu.
__global__ __launch_bounds__(256) void k_comb(
    const float* __restrict__ hp,
    const float* __restrict__ Mp,
    const float* __restrict__ Lp,
    float* __restrict__ out)
{
    const int t = threadIdx.x;
    const int i = blockIdx.x;

    float m0 = Mp[i*NJC+0], m1 = Mp[i*NJC+1], m2 = Mp[i*NJC+2];
    float M  = fmaxf(fmaxf(m0, m1), m2);
    float w0 = __expf(m0 - M), w1 = __expf(m1 - M), w2 = __expf(m2 - M);
    float den = w0*Lp[i*NJC+0] + w1*Lp[i*NJC+1] + w2*Lp[i*NJC+2];
    float inv = 1.0f / den;

    float num = w0 * hp[((size_t)0*NN + i)*CC + t]
              + w1 * hp[((size_t)1*NN + i)*CC + t]
              + w2 * hp[((size_t)2*NN + i)*CC + t];
    float v = num * inv;
    out[i*CC + t] = (v > 0.f) ? v : (__expf(v) - 1.0f);
}

extern "C" void kernel_launch(void* const* d_in, const int* in_sizes, int n_in,
                              void* d_out, int out_size, void* d_ws, size_t ws_size,
                              hipStream_t stream) {
    const float* features = (const float*)d_in[0];
    const float* coords   = (const float*)d_in[1];
    // d_in[2] = adj, unused by forward
    const float* FC       = (const float*)d_in[3];
    const float* fc_w     = (const float*)d_in[4];
    const float* fc_b     = (const float*)d_in[5];
    const float* sc_w     = (const float*)d_in[6];
    const float* sc_b     = (const float*)d_in[7];
    const float* lin_w    = (const float*)d_in[8];
    const float* lin_b    = (const float*)d_in[9];
    float* out = (float*)d_out;

    float* f  = (float*)d_ws;              // N*C
    float* g  = f  + NN*CC;                // C*N
    float* D0 = g  + CC*NN;                // N
    float* D1 = D0 + NN;                   // N
    float* Mp = D1 + NN;                   // N*NJC
    float* Lp = Mp + NN*NJC;               // N*NJC
    float* hp = Lp + NN*NJC;               // NJC*N*C
    float4* ut4;
    {
        size_t off = (size_t)((char*)(hp + (size_t)NJC*NN*CC) - (char*)d_ws);
        off = (off + 15) & ~(size_t)15;
        ut4 = (float4*)((char*)d_ws + off); // (N/3)*C float4, 16B-aligned
    }

    k_prep<<<NN/TI, 768, 0, stream>>>(features, FC, fc_w, fc_b, lin_w, f, g, D0, D1, ut4);
    k_attn<<<(NN/TI)*NJC, 256, 0, stream>>>(f, g, ut4, D0, D1, coords, sc_w, sc_b,
                                            lin_w, lin_b, hp, Mp, Lp);
    k_comb<<<NN, 256, 0, stream>>>(hp, Mp, Lp, out);
}